// Round 1
// baseline (5102.498 us; speedup 1.0000x reference)
//
#include <hip/hip_runtime.h>
#include <cstdint>

typedef __attribute__((ext_vector_type(8))) short bf16x8;
typedef __attribute__((ext_vector_type(4))) float f32x4;

#define AS1 __attribute__((address_space(1)))
#define AS3 __attribute__((address_space(3)))

__device__ __forceinline__ unsigned short f2bf(float f) {
  unsigned int u = __builtin_bit_cast(unsigned int, f);
  return (unsigned short)((u + 0x7fffu + ((u >> 16) & 1u)) >> 16);
}
__device__ __forceinline__ float bf2f(unsigned short h) {
  unsigned int u = ((unsigned int)h) << 16;
  return __builtin_bit_cast(float, u);
}
__device__ __forceinline__ float sigm(float x) { return 1.f / (1.f + __expf(-x)); }
__device__ __forceinline__ float tanh_f(float x) {
  float e = __expf(2.f * x);          // inf-safe: e=inf -> 1, e=0 -> -1
  return 1.f - 2.f / (e + 1.f);
}
__device__ __forceinline__ void gload16(const void* g, void* l) {
  __builtin_amdgcn_global_load_lds((const AS1 unsigned int*)g, (AS3 unsigned int*)l, 16, 0, 0);
}
// XOR-swizzle within a [rows][64]-bf16 tile: spreads the 128B-stride column
// reads across 8 16B slots (T2; both staging-source and ds_read use this).
__device__ __forceinline__ int swz(int e) { return e ^ (((e >> 6) & 7) << 3); }

// ---------------- setup / conversion kernels ----------------

// Wh stack: dst[(g*1024+b)*1024 + k] = Whg[b*1024+k]  (straight bf16 copy)
__global__ __launch_bounds__(256) void conv_wh_kernel(
    const float4* __restrict__ w0, const float4* __restrict__ w1,
    const float4* __restrict__ w2, const float4* __restrict__ w3,
    unsigned long long* __restrict__ dst) {
  int i = blockIdx.x * 256 + threadIdx.x;           // 0 .. 1M-1 (float4 units)
  int g = i >> 18;                                  // 262144 float4 per matrix
  const float4* s = g == 0 ? w0 : g == 1 ? w1 : g == 2 ? w2 : w3;
  float4 v = s[i & 0x3FFFF];
  unsigned long long p = (unsigned long long)f2bf(v.x) |
                         ((unsigned long long)f2bf(v.y) << 16) |
                         ((unsigned long long)f2bf(v.z) << 32) |
                         ((unsigned long long)f2bf(v.w) << 48);
  dst[i] = p;
}

// WiT transpose: dst[(g*1024+j)*1024 + k] = Wig[k*1024+j]  (bf16)
__global__ __launch_bounds__(256) void conv_wiT_kernel(
    const float* __restrict__ w0, const float* __restrict__ w1,
    const float* __restrict__ w2, const float* __restrict__ w3,
    unsigned short* __restrict__ dst) {
  __shared__ unsigned short ls[64][72];
  int bid = blockIdx.x;                 // 0..1023 : 4 gates x 16x16 tiles
  int g = bid >> 8;
  int t2 = bid & 255;
  int tj = t2 & 15, tk = t2 >> 4;
  const float* W = g == 0 ? w0 : g == 1 ? w1 : g == 2 ? w2 : w3;
  int k0 = tk * 64, j0 = tj * 64;
  int ty = threadIdx.x >> 6, tx = threadIdx.x & 63;
#pragma unroll
  for (int r = 0; r < 16; ++r) {
    int k = k0 + ty * 16 + r;
    ls[tx][ty * 16 + r] = f2bf(W[k * 1024 + j0 + tx]);  // ls[j_local][k_local]
  }
  __syncthreads();
#pragma unroll
  for (int r = 0; r < 16; ++r) {
    int jl = ty * 16 + r;
    dst[(size_t)(g * 1024 + j0 + jl) * 1024 + k0 + tx] = ls[jl][tx];
  }
}

__global__ __launch_bounds__(256) void conv_bias_kernel(
    const float* __restrict__ b0, const float* __restrict__ b1,
    const float* __restrict__ b2, const float* __restrict__ b3,
    float* __restrict__ dst) {
  int i = blockIdx.x * 256 + threadIdx.x;  // 0..4095
  const float* s = (i >> 10) == 0 ? b0 : (i >> 10) == 1 ? b1 : (i >> 10) == 2 ? b2 : b3;
  dst[i] = s[i & 1023];
}

__global__ __launch_bounds__(256) void conv_x_kernel(
    const float4* __restrict__ src, unsigned long long* __restrict__ dst, int n4) {
  int i = blockIdx.x * 256 + threadIdx.x;
  if (i < n4) {
    float4 v = src[i];
    dst[i] = (unsigned long long)f2bf(v.x) |
             ((unsigned long long)f2bf(v.y) << 16) |
             ((unsigned long long)f2bf(v.z) << 32) |
             ((unsigned long long)f2bf(v.w) << 48);
  }
}

// ---------------- input-projection GEMM ----------------
// C[m][4096] (bf16) = A[m][1024](bf16) @ WiT[n][1024]^T ; tile 128x128, BK=64,
// 4 waves (2x2), dbuf LDS, global_load_lds(16B), XOR-swizzled staging+reads.
__global__ __launch_bounds__(256) void xproj_gemm_kernel(
    const unsigned short* __restrict__ A,   // [Mc][1024]
    const unsigned short* __restrict__ Bt,  // [4096][1024]
    unsigned short* __restrict__ C,         // [Mc][4096]
    int Mc) {
  __shared__ unsigned short lsA[2][128 * 64];
  __shared__ unsigned short lsB[2][128 * 64];
  int bx = blockIdx.x;
  int bm = bx >> 5, bn = bx & 31;
  int m0 = bm * 128, n0 = bn * 128;
  int tid = threadIdx.x, w = tid >> 6, lane = tid & 63;
  int wm = w >> 1, wn = w & 1;
  int l15 = lane & 15, l4 = lane >> 4;

  f32x4 acc[4][4];
#pragma unroll
  for (int i = 0; i < 4; ++i)
#pragma unroll
    for (int j = 0; j < 4; ++j) acc[i][j] = (f32x4)0.f;

  auto stage = [&](int buf, int kk) {
#pragma unroll
    for (int ld = 0; ld < 4; ++ld) {
      int cid = ld * 256 + tid;
      int r = cid >> 3, kc = (cid & 7) * 8;
      int sk = kk + (kc ^ ((r & 7) << 3));
      gload16(&A[(size_t)(m0 + r) * 1024 + sk], &lsA[buf][(ld * 256 + w * 64) * 8]);
      gload16(&Bt[(size_t)(n0 + r) * 1024 + sk], &lsB[buf][(ld * 256 + w * 64) * 8]);
    }
  };
  auto compute = [&](int buf) {
    bf16x8 af[4][2], bfr[4][2];
#pragma unroll
    for (int cm = 0; cm < 4; ++cm)
#pragma unroll
      for (int ks = 0; ks < 2; ++ks) {
        int e = (wm * 64 + cm * 16 + l15) * 64 + ks * 32 + l4 * 8;
        af[cm][ks] = *(const bf16x8*)&lsA[buf][swz(e)];
      }
#pragma unroll
    for (int cn = 0; cn < 4; ++cn)
#pragma unroll
      for (int ks = 0; ks < 2; ++ks) {
        int e = (wn * 64 + cn * 16 + l15) * 64 + ks * 32 + l4 * 8;
        bfr[cn][ks] = *(const bf16x8*)&lsB[buf][swz(e)];
      }
#pragma unroll
    for (int cm = 0; cm < 4; ++cm)
#pragma unroll
      for (int cn = 0; cn < 4; ++cn)
#pragma unroll
        for (int ks = 0; ks < 2; ++ks)
          acc[cm][cn] = __builtin_amdgcn_mfma_f32_16x16x32_bf16(
              af[cm][ks], bfr[cn][ks], acc[cm][cn], 0, 0, 0);
  };

  stage(0, 0);
  __syncthreads();
  int cur = 0;
  for (int ks = 1; ks < 16; ++ks) {
    stage(cur ^ 1, ks * 64);
    compute(cur);
    __syncthreads();
    cur ^= 1;
  }
  compute(cur);

#pragma unroll
  for (int cm = 0; cm < 4; ++cm)
#pragma unroll
    for (int cn = 0; cn < 4; ++cn)
#pragma unroll
      for (int r = 0; r < 4; ++r) {
        int row = m0 + wm * 64 + cm * 16 + l4 * 4 + r;
        int col = n0 + wn * 64 + cn * 16 + l15;
        C[(size_t)row * 4096 + col] = f2bf(acc[cm][cn][r]);
      }
}

// ---------------- fused LSTM step ----------------
// Per block: tile (64 batch rows x 64 hidden cols) for ALL 4 gates.
// A = Wh stack rows {g*1024+b}, B = hT[j][k]. 8 waves (4 row x 2 col).
__global__ __launch_bounds__(512) void lstm_step_kernel(
    const unsigned short* __restrict__ Wh,   // [4096][1024]
    const unsigned short* __restrict__ hT,   // [1024][1024]  hT[j][k]=h[k][j]
    const unsigned short* __restrict__ Xp,   // [1024][4096]  this step's x-proj
    const float* __restrict__ bias,          // [4096]
    float* __restrict__ cst,                 // [1024*1024] fp32 cell state
    float* __restrict__ out_h,               // d_out + t*1M
    float* __restrict__ out_ht,              // d_out + T*1M
    float* __restrict__ out_ct,              // d_out + T*1M + 1M
    unsigned short* __restrict__ hT_next,    // other hT buffer
    int isLast) {
  __shared__ unsigned short lsA[2][256 * 64];  // 4 gates x 64 rows x BK
  __shared__ unsigned short lsB[2][64 * 64];
  int bx = blockIdx.x;
  int bb = bx >> 4, bj = bx & 15;
  int b0 = bb * 64, j0 = bj * 64;
  int tid = threadIdx.x, w = tid >> 6, lane = tid & 63;
  int wm = w >> 1, wn = w & 1;
  int l15 = lane & 15, l4 = lane >> 4;

  f32x4 acc[4][2];
#pragma unroll
  for (int g = 0; g < 4; ++g)
#pragma unroll
    for (int n = 0; n < 2; ++n) acc[g][n] = (f32x4)0.f;

  auto stage = [&](int buf, int kk) {
#pragma unroll
    for (int ld = 0; ld < 4; ++ld) {
      int cid = ld * 512 + tid;
      int r = cid >> 3, kc = (cid & 7) * 8;       // r: 0..255 local row
      int sk = kk + (kc ^ ((r & 7) << 3));
      int grow = (r >> 6) * 1024 + b0 + (r & 63); // gate*1024 + batch row
      gload16(&Wh[(size_t)grow * 1024 + sk], &lsA[buf][(ld * 512 + w * 64) * 8]);
    }
    {
      int r = tid >> 3, kc = (tid & 7) * 8;       // r: 0..63
      int sk = kk + (kc ^ ((r & 7) << 3));
      gload16(&hT[(size_t)(j0 + r) * 1024 + sk], &lsB[buf][w * 512]);
    }
  };
  auto compute = [&](int buf) {
    bf16x8 af[4][2], bfr[2][2];
#pragma unroll
    for (int g = 0; g < 4; ++g)
#pragma unroll
      for (int ks = 0; ks < 2; ++ks) {
        int e = (g * 64 + wm * 16 + l15) * 64 + ks * 32 + l4 * 8;
        af[g][ks] = *(const bf16x8*)&lsA[buf][swz(e)];
      }
#pragma unroll
    for (int n = 0; n < 2; ++n)
#pragma unroll
      for (int ks = 0; ks < 2; ++ks) {
        int e = (wn * 32 + n * 16 + l15) * 64 + ks * 32 + l4 * 8;
        bfr[n][ks] = *(const bf16x8*)&lsB[buf][swz(e)];
      }
#pragma unroll
    for (int g = 0; g < 4; ++g)
#pragma unroll
      for (int n = 0; n < 2; ++n)
#pragma unroll
        for (int ks = 0; ks < 2; ++ks)
          acc[g][n] = __builtin_amdgcn_mfma_f32_16x16x32_bf16(
              af[g][ks], bfr[n][ks], acc[g][n], 0, 0, 0);
  };

  stage(0, 0);
  __syncthreads();
  int cur = 0;
  for (int ks = 1; ks < 16; ++ks) {
    stage(cur ^ 1, ks * 64);
    compute(cur);
    __syncthreads();
    cur ^= 1;
  }
  compute(cur);

  // epilogue: gates + cell/hidden update
#pragma unroll
  for (int n = 0; n < 2; ++n) {
    int j = j0 + wn * 32 + n * 16 + l15;
    float bi_ = bias[j];
    float bf_ = bias[1024 + j];
    float bg_ = bias[2048 + j];
    float bo_ = bias[3072 + j];
    int bbase = b0 + wm * 16 + l4 * 4;
    float hn[4], cn[4];
#pragma unroll
    for (int r = 0; r < 4; ++r) {
      int b = bbase + r;
      size_t xb = (size_t)b * 4096;
      float pi = acc[0][n][r] + bf2f(Xp[xb + j]) + bi_;
      float pf = acc[1][n][r] + bf2f(Xp[xb + 1024 + j]) + bf_;
      float pg = acc[2][n][r] + bf2f(Xp[xb + 2048 + j]) + bg_;
      float po = acc[3][n][r] + bf2f(Xp[xb + 3072 + j]) + bo_;
      float ig = sigm(pi), fg = sigm(pf), gg = tanh_f(pg), og = sigm(po);
      float c_new = fg * cst[(size_t)b * 1024 + j] + ig * gg;
      cst[(size_t)b * 1024 + j] = c_new;
      cn[r] = c_new;
      hn[r] = og * tanh_f(c_new);
      out_h[(size_t)b * 1024 + j] = hn[r];
    }
    unsigned long long hp = (unsigned long long)f2bf(hn[0]) |
                            ((unsigned long long)f2bf(hn[1]) << 16) |
                            ((unsigned long long)f2bf(hn[2]) << 32) |
                            ((unsigned long long)f2bf(hn[3]) << 48);
    *(unsigned long long*)&hT_next[(size_t)j * 1024 + bbase] = hp;
    if (isLast) {
#pragma unroll
      for (int r = 0; r < 4; ++r) {
        int b = bbase + r;
        out_ht[(size_t)b * 1024 + j] = hn[r];
        out_ct[(size_t)b * 1024 + j] = cn[r];
      }
    }
  }
}

// ---------------- host ----------------
extern "C" void kernel_launch(void* const* d_in, const int* in_sizes, int n_in,
                              void* d_out, int out_size, void* d_ws, size_t ws_size,
                              hipStream_t stream) {
  const float* X   = (const float*)d_in[0];
  const float* Wii = (const float*)d_in[1];
  const float* Whi = (const float*)d_in[2];
  const float* bi  = (const float*)d_in[3];
  const float* Wif = (const float*)d_in[4];
  const float* Whf = (const float*)d_in[5];
  const float* bfv = (const float*)d_in[6];
  const float* Wig = (const float*)d_in[7];
  const float* Whg = (const float*)d_in[8];
  const float* bg  = (const float*)d_in[9];
  const float* Wio = (const float*)d_in[10];
  const float* Who = (const float*)d_in[11];
  const float* bo  = (const float*)d_in[12];
  float* out = (float*)d_out;

  char* wsp = (char*)d_ws;
  size_t off = 0;
  auto walloc = [&](size_t b) -> void* {
    void* p = wsp + off;
    off += (b + 255) & ~(size_t)255;
    return p;
  };
  unsigned short* WiT = (unsigned short*)walloc(4096ull * 1024 * 2);
  unsigned short* Wh  = (unsigned short*)walloc(4096ull * 1024 * 2);
  float* bias = (float*)walloc(4096 * 4);
  unsigned short* hT0 = (unsigned short*)walloc(1024ull * 1024 * 2);
  unsigned short* hT1 = (unsigned short*)walloc(1024ull * 1024 * 2);
  float* cbuf = (float*)walloc(1024ull * 1024 * 4);
  size_t fixed = off;

  long long avail = (long long)ws_size - (long long)fixed - (1ll << 20);
  int Tc = (int)(avail / (10ll << 20));   // 2MB Xbf + 8MB Xproj per step
  if (Tc < 1) Tc = 1;
  if (Tc > 128) Tc = 128;
  unsigned short* Xbf = (unsigned short*)walloc((size_t)Tc * 1024 * 1024 * 2);
  unsigned short* Xp  = (unsigned short*)walloc((size_t)Tc * 1024 * 4096 * 2);

  conv_wh_kernel<<<4096, 256, 0, stream>>>((const float4*)Whi, (const float4*)Whf,
                                           (const float4*)Whg, (const float4*)Who,
                                           (unsigned long long*)Wh);
  conv_wiT_kernel<<<1024, 256, 0, stream>>>(Wii, Wif, Wig, Wio, WiT);
  conv_bias_kernel<<<16, 256, 0, stream>>>(bi, bfv, bg, bo, bias);
  hipMemsetAsync(hT0, 0, 1024ull * 1024 * 2, stream);
  hipMemsetAsync(cbuf, 0, 1024ull * 1024 * 4, stream);

  for (int t0 = 0; t0 < 128; t0 += Tc) {
    int tc = (128 - t0 < Tc) ? (128 - t0) : Tc;
    int n4 = tc * 262144;
    conv_x_kernel<<<n4 / 256, 256, 0, stream>>>(
        (const float4*)(X + (size_t)t0 * 1048576),
        (unsigned long long*)Xbf, n4);
    xproj_gemm_kernel<<<tc * 256, 256, 0, stream>>>(Xbf, WiT, Xp, tc * 1024);
    for (int i = 0; i < tc; ++i) {
      int t = t0 + i;
      lstm_step_kernel<<<256, 512, 0, stream>>>(
          Wh, (t & 1) ? hT1 : hT0,
          Xp + (size_t)i * 1024 * 4096,
          bias, cbuf,
          out + (size_t)t * 1048576,
          out + 134217728ull,
          out + 135266304ull,
          (t & 1) ? hT0 : hT1,
          (t == 127) ? 1 : 0);
    }
  }
}

// Round 2
// 4386.636 us; speedup vs baseline: 1.1632x; 1.1632x over previous
//
#include <hip/hip_runtime.h>
#include <cstdint>

typedef __attribute__((ext_vector_type(8))) short bf16x8;
typedef __attribute__((ext_vector_type(4))) float f32x4;

#define AS1 __attribute__((address_space(1)))
#define AS3 __attribute__((address_space(3)))

__device__ __forceinline__ unsigned short f2bf(float f) {
  unsigned int u = __builtin_bit_cast(unsigned int, f);
  return (unsigned short)((u + 0x7fffu + ((u >> 16) & 1u)) >> 16);
}
__device__ __forceinline__ float bf2f(unsigned short h) {
  unsigned int u = ((unsigned int)h) << 16;
  return __builtin_bit_cast(float, u);
}
__device__ __forceinline__ float sigm(float x) { return 1.f / (1.f + __expf(-x)); }
__device__ __forceinline__ float tanh_f(float x) {
  float e = __expf(2.f * x);          // inf-safe: e=inf -> 1, e=0 -> -1
  return 1.f - 2.f / (e + 1.f);
}
__device__ __forceinline__ void gload16(const void* g, void* l) {
  __builtin_amdgcn_global_load_lds((const AS1 unsigned int*)g, (AS3 unsigned int*)l, 16, 0, 0);
}
// XOR-swizzle within a [rows][64]-bf16 tile: spreads the 128B-stride column
// reads across 8 16B slots (T2; staging pre-swizzles the GLOBAL source, LDS
// dest stays linear, reads apply the same involution — rule #21).
__device__ __forceinline__ int swz(int e) { return e ^ (((e >> 6) & 7) << 3); }

// ---------------- setup / conversion kernels ----------------

__global__ __launch_bounds__(256) void conv_wh_kernel(
    const float4* __restrict__ w0, const float4* __restrict__ w1,
    const float4* __restrict__ w2, const float4* __restrict__ w3,
    unsigned long long* __restrict__ dst) {
  int i = blockIdx.x * 256 + threadIdx.x;           // 0 .. 1M-1 (float4 units)
  int g = i >> 18;                                  // 262144 float4 per matrix
  const float4* s = g == 0 ? w0 : g == 1 ? w1 : g == 2 ? w2 : w3;
  float4 v = s[i & 0x3FFFF];
  unsigned long long p = (unsigned long long)f2bf(v.x) |
                         ((unsigned long long)f2bf(v.y) << 16) |
                         ((unsigned long long)f2bf(v.z) << 32) |
                         ((unsigned long long)f2bf(v.w) << 48);
  dst[i] = p;
}

__global__ __launch_bounds__(256) void conv_wiT_kernel(
    const float* __restrict__ w0, const float* __restrict__ w1,
    const float* __restrict__ w2, const float* __restrict__ w3,
    unsigned short* __restrict__ dst) {
  __shared__ unsigned short ls[64][72];
  int bid = blockIdx.x;                 // 0..1023 : 4 gates x 16x16 tiles
  int g = bid >> 8;
  int t2 = bid & 255;
  int tj = t2 & 15, tk = t2 >> 4;
  const float* W = g == 0 ? w0 : g == 1 ? w1 : g == 2 ? w2 : w3;
  int k0 = tk * 64, j0 = tj * 64;
  int ty = threadIdx.x >> 6, tx = threadIdx.x & 63;
#pragma unroll
  for (int r = 0; r < 16; ++r) {
    int k = k0 + ty * 16 + r;
    ls[tx][ty * 16 + r] = f2bf(W[k * 1024 + j0 + tx]);  // ls[j_local][k_local]
  }
  __syncthreads();
#pragma unroll
  for (int r = 0; r < 16; ++r) {
    int jl = ty * 16 + r;
    dst[(size_t)(g * 1024 + j0 + jl) * 1024 + k0 + tx] = ls[jl][tx];
  }
}

__global__ __launch_bounds__(256) void conv_bias_kernel(
    const float* __restrict__ b0, const float* __restrict__ b1,
    const float* __restrict__ b2, const float* __restrict__ b3,
    float* __restrict__ dst) {
  int i = blockIdx.x * 256 + threadIdx.x;  // 0..4095
  const float* s = (i >> 10) == 0 ? b0 : (i >> 10) == 1 ? b1 : (i >> 10) == 2 ? b2 : b3;
  dst[i] = s[i & 1023];
}

__global__ __launch_bounds__(256) void conv_x_kernel(
    const float4* __restrict__ src, unsigned long long* __restrict__ dst, int n4) {
  int i = blockIdx.x * 256 + threadIdx.x;
  if (i < n4) {
    float4 v = src[i];
    dst[i] = (unsigned long long)f2bf(v.x) |
             ((unsigned long long)f2bf(v.y) << 16) |
             ((unsigned long long)f2bf(v.z) << 32) |
             ((unsigned long long)f2bf(v.w) << 48);
  }
}

// ---------------- input-projection GEMM ----------------
// m97 structure: SINGLE-buffer LDS (32KB -> ~4 blocks/CU, cross-block TLP
// hides the barrier drain), 2 syncs per K-iter, global_load_lds(16B),
// XOR-swizzled staging+reads. 128x128 tile, BK=64, 4 waves (2x2).
__global__ __launch_bounds__(256) void xproj_gemm_kernel(
    const unsigned short* __restrict__ A,   // [Mc][1024]
    const unsigned short* __restrict__ Bt,  // [4096][1024]
    unsigned short* __restrict__ C,         // [Mc][4096]
    int Mc) {
  __shared__ unsigned short lsA[128 * 64];
  __shared__ unsigned short lsB[128 * 64];
  int bx = blockIdx.x;
  int bm = bx >> 5, bn = bx & 31;
  int m0 = bm * 128, n0 = bn * 128;
  int tid = threadIdx.x, w = tid >> 6, lane = tid & 63;
  int wm = w >> 1, wn = w & 1;
  int l15 = lane & 15, l4 = lane >> 4;

  f32x4 acc[4][4];
#pragma unroll
  for (int i = 0; i < 4; ++i)
#pragma unroll
    for (int j = 0; j < 4; ++j) acc[i][j] = (f32x4)0.f;

  for (int ks = 0; ks < 16; ++ks) {
    int kk = ks * 64;
    __syncthreads();   // everyone done reading previous tile
#pragma unroll
    for (int ld = 0; ld < 4; ++ld) {
      int cid = ld * 256 + tid;
      int r = cid >> 3, kc = (cid & 7) * 8;
      int sk = kk + (kc ^ ((r & 7) << 3));
      gload16(&A[(size_t)(m0 + r) * 1024 + sk], &lsA[(ld * 256 + w * 64) * 8]);
      gload16(&Bt[(size_t)(n0 + r) * 1024 + sk], &lsB[(ld * 256 + w * 64) * 8]);
    }
    __syncthreads();   // data ready (drains vmcnt)
    bf16x8 af[4][2], bfr[4][2];
#pragma unroll
    for (int cm = 0; cm < 4; ++cm)
#pragma unroll
      for (int kss = 0; kss < 2; ++kss) {
        int e = (wm * 64 + cm * 16 + l15) * 64 + kss * 32 + l4 * 8;
        af[cm][kss] = *(const bf16x8*)&lsA[swz(e)];
      }
#pragma unroll
    for (int cn = 0; cn < 4; ++cn)
#pragma unroll
      for (int kss = 0; kss < 2; ++kss) {
        int e = (wn * 64 + cn * 16 + l15) * 64 + kss * 32 + l4 * 8;
        bfr[cn][kss] = *(const bf16x8*)&lsB[swz(e)];
      }
#pragma unroll
    for (int cm = 0; cm < 4; ++cm)
#pragma unroll
      for (int cn = 0; cn < 4; ++cn)
#pragma unroll
        for (int kss = 0; kss < 2; ++kss)
          acc[cm][cn] = __builtin_amdgcn_mfma_f32_16x16x32_bf16(
              af[cm][kss], bfr[cn][kss], acc[cm][cn], 0, 0, 0);
  }

#pragma unroll
  for (int cm = 0; cm < 4; ++cm)
#pragma unroll
    for (int cn = 0; cn < 4; ++cn)
#pragma unroll
      for (int r = 0; r < 4; ++r) {
        int row = m0 + wm * 64 + cm * 16 + l4 * 4 + r;
        int col = n0 + wn * 64 + cn * 16 + l15;
        C[(size_t)row * 4096 + col] = f2bf(acc[cm][cn][r]);
      }
}

// ---------------- fused LSTM step ----------------
// Per block: tile (64 batch rows x 64 hidden cols) for ALL 4 gates.
// XCD-aware tile map: XCD x owns bb in {2x,2x+1} and all bj, so per-XCD
// working set = 1MB Wh-slice + 2MB hT -> L2-resident staging.
// 3-buffer, 2-deep-prefetch pipeline with counted vmcnt (10/5/0) and raw
// s_barriers; gload_lds loads stay in flight across barriers (T3+T4).
__global__ __launch_bounds__(512) void lstm_step_kernel(
    const unsigned short* __restrict__ Wh,   // [4096][1024]
    const unsigned short* __restrict__ hT,   // [1024][1024]  hT[j][k]=h[k][j]
    const unsigned short* __restrict__ Xp,   // [1024][4096]  this step's x-proj
    const float* __restrict__ bias,          // [4096]
    float* __restrict__ cst,                 // [1024*1024] fp32 cell state
    float* __restrict__ out_h,               // d_out + t*1M
    float* __restrict__ out_ht,              // d_out + T*1M
    float* __restrict__ out_ct,              // d_out + T*1M + 1M
    unsigned short* __restrict__ hT_next,    // other hT buffer
    int isLast) {
  __shared__ unsigned short lsA[3][256 * 64];  // 4 gates x 64 rows x BK, x3 buf
  __shared__ unsigned short lsB[3][64 * 64];
  int bx = blockIdx.x;
  int xcd = bx & 7, idx = bx >> 3;             // block->XCD is round-robin %8
  int bb = xcd * 2 + (idx & 1);                // XCD-local Wh slice
  int bj = idx >> 1;
  int b0 = bb * 64, j0 = bj * 64;
  int tid = threadIdx.x, w = tid >> 6, lane = tid & 63;
  int wm = w >> 1, wn = w & 1;
  int l15 = lane & 15, l4 = lane >> 4;

  f32x4 acc[4][2];
#pragma unroll
  for (int g = 0; g < 4; ++g)
#pragma unroll
    for (int n = 0; n < 2; ++n) acc[g][n] = (f32x4)0.f;

  auto stage = [&](int buf, int kk) {          // 5 gload16 per thread
#pragma unroll
    for (int ld = 0; ld < 4; ++ld) {
      int cid = ld * 512 + tid;
      int r = cid >> 3, kc = (cid & 7) * 8;    // r: 0..255 local row
      int sk = kk + (kc ^ ((r & 7) << 3));
      int grow = (r >> 6) * 1024 + b0 + (r & 63);
      gload16(&Wh[(size_t)grow * 1024 + sk], &lsA[buf][(ld * 512 + w * 64) * 8]);
    }
    {
      int r = tid >> 3, kc = (tid & 7) * 8;    // r: 0..63
      int sk = kk + (kc ^ ((r & 7) << 3));
      gload16(&hT[(size_t)(j0 + r) * 1024 + sk], &lsB[buf][w * 512]);
    }
  };
  auto compute = [&](int buf) {
    bf16x8 af[4][2], bfr[2][2];
#pragma unroll
    for (int g = 0; g < 4; ++g)
#pragma unroll
      for (int kss = 0; kss < 2; ++kss) {
        int e = (g * 64 + wm * 16 + l15) * 64 + kss * 32 + l4 * 8;
        af[g][kss] = *(const bf16x8*)&lsA[buf][swz(e)];
      }
#pragma unroll
    for (int n = 0; n < 2; ++n)
#pragma unroll
      for (int kss = 0; kss < 2; ++kss) {
        int e = (wn * 32 + n * 16 + l15) * 64 + kss * 32 + l4 * 8;
        bfr[n][kss] = *(const bf16x8*)&lsB[buf][swz(e)];
      }
#pragma unroll
    for (int g = 0; g < 4; ++g)
#pragma unroll
      for (int n = 0; n < 2; ++n)
#pragma unroll
        for (int kss = 0; kss < 2; ++kss)
          acc[g][n] = __builtin_amdgcn_mfma_f32_16x16x32_bf16(
              af[g][kss], bfr[n][kss], acc[g][n], 0, 0, 0);
  };

  // prologue: 2 stages in flight (10 outstanding loads/thread)
  stage(0, 0);
  stage(1, 64);
#pragma unroll
  for (int i = 0; i < 16; ++i) {
    if (i + 2 < 16) stage((i + 2) % 3, (i + 2) * 64);  // issue-early
    // wait for stage i only: newer stages stay in flight across the barrier
    if (i < 14)        asm volatile("s_waitcnt vmcnt(10)" ::: "memory");
    else if (i == 14)  asm volatile("s_waitcnt vmcnt(5)" ::: "memory");
    else               asm volatile("s_waitcnt vmcnt(0)" ::: "memory");
    __builtin_amdgcn_sched_barrier(0);
    __builtin_amdgcn_s_barrier();              // all waves' stage(i) landed
    __builtin_amdgcn_sched_barrier(0);
    compute(i % 3);
    asm volatile("s_waitcnt lgkmcnt(0)" ::: "memory");  // my ds_reads retired
    __builtin_amdgcn_sched_barrier(0);
    __builtin_amdgcn_s_barrier();              // buf (i)%3 free for restage
    __builtin_amdgcn_sched_barrier(0);
  }

  // epilogue: gates + cell/hidden update
#pragma unroll
  for (int n = 0; n < 2; ++n) {
    int j = j0 + wn * 32 + n * 16 + l15;
    float bi_ = bias[j];
    float bf_ = bias[1024 + j];
    float bg_ = bias[2048 + j];
    float bo_ = bias[3072 + j];
    int bbase = b0 + wm * 16 + l4 * 4;
    float hn[4], cn[4];
#pragma unroll
    for (int r = 0; r < 4; ++r) {
      int b = bbase + r;
      size_t xb = (size_t)b * 4096;
      float pi = acc[0][n][r] + bf2f(Xp[xb + j]) + bi_;
      float pf = acc[1][n][r] + bf2f(Xp[xb + 1024 + j]) + bf_;
      float pg = acc[2][n][r] + bf2f(Xp[xb + 2048 + j]) + bg_;
      float po = acc[3][n][r] + bf2f(Xp[xb + 3072 + j]) + bo_;
      float ig = sigm(pi), fg = sigm(pf), gg = tanh_f(pg), og = sigm(po);
      float c_new = fg * cst[(size_t)b * 1024 + j] + ig * gg;
      cst[(size_t)b * 1024 + j] = c_new;
      cn[r] = c_new;
      hn[r] = og * tanh_f(c_new);
      out_h[(size_t)b * 1024 + j] = hn[r];
    }
    unsigned long long hp = (unsigned long long)f2bf(hn[0]) |
                            ((unsigned long long)f2bf(hn[1]) << 16) |
                            ((unsigned long long)f2bf(hn[2]) << 32) |
                            ((unsigned long long)f2bf(hn[3]) << 48);
    *(unsigned long long*)&hT_next[(size_t)j * 1024 + bbase] = hp;
    if (isLast) {
#pragma unroll
      for (int r = 0; r < 4; ++r) {
        int b = bbase + r;
        out_ht[(size_t)b * 1024 + j] = hn[r];
        out_ct[(size_t)b * 1024 + j] = cn[r];
      }
    }
  }
}

// ---------------- host ----------------
extern "C" void kernel_launch(void* const* d_in, const int* in_sizes, int n_in,
                              void* d_out, int out_size, void* d_ws, size_t ws_size,
                              hipStream_t stream) {
  const float* X   = (const float*)d_in[0];
  const float* Wii = (const float*)d_in[1];
  const float* Whi = (const float*)d_in[2];
  const float* bi  = (const float*)d_in[3];
  const float* Wif = (const float*)d_in[4];
  const float* Whf = (const float*)d_in[5];
  const float* bfv = (const float*)d_in[6];
  const float* Wig = (const float*)d_in[7];
  const float* Whg = (const float*)d_in[8];
  const float* bg  = (const float*)d_in[9];
  const float* Wio = (const float*)d_in[10];
  const float* Who = (const float*)d_in[11];
  const float* bo  = (const float*)d_in[12];
  float* out = (float*)d_out;

  char* wsp = (char*)d_ws;
  size_t off = 0;
  auto walloc = [&](size_t b) -> void* {
    void* p = wsp + off;
    off += (b + 255) & ~(size_t)255;
    return p;
  };
  unsigned short* WiT = (unsigned short*)walloc(4096ull * 1024 * 2);
  unsigned short* Wh  = (unsigned short*)walloc(4096ull * 1024 * 2);
  float* bias = (float*)walloc(4096 * 4);
  unsigned short* hT0 = (unsigned short*)walloc(1024ull * 1024 * 2);
  unsigned short* hT1 = (unsigned short*)walloc(1024ull * 1024 * 2);
  float* cbuf = (float*)walloc(1024ull * 1024 * 4);
  size_t fixed = off;

  long long avail = (long long)ws_size - (long long)fixed - (1ll << 20);
  int Tc = (int)(avail / (10ll << 20));   // 2MB Xbf + 8MB Xproj per step
  if (Tc < 1) Tc = 1;
  if (Tc > 128) Tc = 128;
  unsigned short* Xbf = (unsigned short*)walloc((size_t)Tc * 1024 * 1024 * 2);
  unsigned short* Xp  = (unsigned short*)walloc((size_t)Tc * 1024 * 4096 * 2);

  conv_wh_kernel<<<4096, 256, 0, stream>>>((const float4*)Whi, (const float4*)Whf,
                                           (const float4*)Whg, (const float4*)Who,
                                           (unsigned long long*)Wh);
  conv_wiT_kernel<<<1024, 256, 0, stream>>>(Wii, Wif, Wig, Wio, WiT);
  conv_bias_kernel<<<16, 256, 0, stream>>>(bi, bfv, bg, bo, bias);
  hipMemsetAsync(hT0, 0, 1024ull * 1024 * 2, stream);
  hipMemsetAsync(cbuf, 0, 1024ull * 1024 * 4, stream);

  for (int t0 = 0; t0 < 128; t0 += Tc) {
    int tc = (128 - t0 < Tc) ? (128 - t0) : Tc;
    int n4 = tc * 262144;
    conv_x_kernel<<<n4 / 256, 256, 0, stream>>>(
        (const float4*)(X + (size_t)t0 * 1048576),
        (unsigned long long*)Xbf, n4);
    xproj_gemm_kernel<<<tc * 256, 256, 0, stream>>>(Xbf, WiT, Xp, tc * 1024);
    for (int i = 0; i < tc; ++i) {
      int t = t0 + i;
      lstm_step_kernel<<<256, 512, 0, stream>>>(
          Wh, (t & 1) ? hT1 : hT0,
          Xp + (size_t)i * 1024 * 4096,
          bias, cbuf,
          out + (size_t)t * 1048576,
          out + 134217728ull,
          out + 135266304ull,
          (t & 1) ? hT0 : hT1,
          (t == 127) ? 1 : 0);
    }
  }
}